// Round 2
// baseline (246.398 us; speedup 1.0000x reference)
//
#include <hip/hip_runtime.h>
#include <hip/hip_bf16.h>
#include <stdint.h>

// Problem constants: B=2, S=2048, D_MODEL=1024, H=16, Dk=64. M = B*S = 4096.
typedef unsigned short u16;
typedef __attribute__((ext_vector_type(8))) short short8;
typedef __attribute__((ext_vector_type(8))) __bf16 bf16x8;
typedef __attribute__((ext_vector_type(4))) float f32x4;

#if defined(__has_builtin)
#if __has_builtin(__builtin_amdgcn_global_load_lds)
#define USE_GLLDS 1
#endif
#endif

__device__ __forceinline__ u16 f2bf(float f) {
  __hip_bfloat16 h = __float2bfloat16(f);
  return __builtin_bit_cast(u16, h);
}

__device__ __forceinline__ f32x4 mfma16(bf16x8 a, bf16x8 b, f32x4 c) {
  return __builtin_amdgcn_mfma_f32_16x16x32_bf16(a, b, c, 0, 0, 0);
}

#ifdef USE_GLLDS
__device__ __forceinline__ void async_cp16(const void* g, void* l) {
  __builtin_amdgcn_global_load_lds(
      (const __attribute__((address_space(1))) void*)g,
      (__attribute__((address_space(3))) void*)l, 16, 0, 0);
}
#endif

// ---------------------------------------------------------------------------
// Kernel 1: fp32 -> bf16 conversion of q,k,v (4M each) and w_q,w_k,w_v,w_o (1M
// each) into one contiguous 16M-element bf16 region at the start of d_ws.
// ---------------------------------------------------------------------------
__global__ __launch_bounds__(256) void cvt_all(
    const float* __restrict__ q, const float* __restrict__ k,
    const float* __restrict__ v, const float* __restrict__ w0,
    const float* __restrict__ w1, const float* __restrict__ w2,
    const float* __restrict__ w3, u16* __restrict__ dst) {
  size_t i = ((size_t)blockIdx.x * 256 + threadIdx.x) * 8;
  const size_t M1 = 1u << 20;
  const float* s;
  size_t base;
  if (i < 4 * M1) { s = q; base = 0; }
  else if (i < 8 * M1) { s = k; base = 4 * M1; }
  else if (i < 12 * M1) { s = v; base = 8 * M1; }
  else if (i < 13 * M1) { s = w0; base = 12 * M1; }
  else if (i < 14 * M1) { s = w1; base = 13 * M1; }
  else if (i < 15 * M1) { s = w2; base = 14 * M1; }
  else { s = w3; base = 15 * M1; }
  const float4 a = *(const float4*)(s + (i - base));
  const float4 b = *(const float4*)(s + (i - base) + 4);
  short8 r;
  r[0] = (short)f2bf(a.x); r[1] = (short)f2bf(a.y);
  r[2] = (short)f2bf(a.z); r[3] = (short)f2bf(a.w);
  r[4] = (short)f2bf(b.x); r[5] = (short)f2bf(b.y);
  r[6] = (short)f2bf(b.z); r[7] = (short)f2bf(b.w);
  *(short8*)(dst + i) = r;
}

// ---------------------------------------------------------------------------
// GEMM: C[M=4096, N=1024] = X[4096,1024] * W[1024,1024]^T + bias.
// Both X and W are K-contiguous -> both MFMA operands load 8 contiguous bf16.
// 128x128 tile, BK=64, 4 waves (each 64x64 quadrant = 4x4 16x16 frags).
// SPLIT=true: write bf16 split-head [B,H,S,64]; else fp32 row-major + bias.
// ---------------------------------------------------------------------------
template <bool SPLIT>
__device__ __forceinline__ void gemm_body(const u16* __restrict__ X,
                                          const u16* __restrict__ W,
                                          const float* __restrict__ bias,
                                          void* __restrict__ outp) {
  __shared__ u16 Al[128 * 64];
  __shared__ u16 Bl[128 * 64];
  const int tid = threadIdx.x;
  const int wv = tid >> 6, l = tid & 63;
  const int wr = wv >> 1, wc = wv & 1;
  const int m0 = blockIdx.y * 128, n0 = blockIdx.x * 128;
  const int lrow = l & 15, lk = (l >> 4) * 8;

  f32x4 acc[4][4];
#pragma unroll
  for (int i = 0; i < 4; ++i)
#pragma unroll
    for (int j = 0; j < 4; ++j) acc[i][j] = (f32x4){0.f, 0.f, 0.f, 0.f};

  const u16* Asrc = X + (size_t)(m0 + (tid >> 3)) * 1024 + (tid & 7) * 8;
  const u16* Bsrc = W + (size_t)(n0 + (tid >> 3)) * 1024 + (tid & 7) * 8;

  for (int kt = 0; kt < 1024; kt += 64) {
#ifdef USE_GLLDS
#pragma unroll
    for (int p = 0; p < 4; ++p) {
      async_cp16(Asrc + (size_t)p * 32 * 1024 + kt, &Al[p * 2048 + wv * 512]);
      async_cp16(Bsrc + (size_t)p * 32 * 1024 + kt, &Bl[p * 2048 + wv * 512]);
    }
#else
    short8 ar[4], br[4];
#pragma unroll
    for (int p = 0; p < 4; ++p) {
      ar[p] = *(const short8*)(Asrc + (size_t)p * 32 * 1024 + kt);
      br[p] = *(const short8*)(Bsrc + (size_t)p * 32 * 1024 + kt);
    }
#pragma unroll
    for (int p = 0; p < 4; ++p) {
      *(short8*)&Al[p * 2048 + tid * 8] = ar[p];
      *(short8*)&Bl[p * 2048 + tid * 8] = br[p];
    }
#endif
    __syncthreads();
#pragma unroll
    for (int ks = 0; ks < 2; ++ks) {
      bf16x8 af[4], bf[4];
#pragma unroll
      for (int mf = 0; mf < 4; ++mf)
        af[mf] = *(const bf16x8*)&Al[(wr * 64 + mf * 16 + lrow) * 64 + ks * 32 + lk];
#pragma unroll
      for (int nf = 0; nf < 4; ++nf)
        bf[nf] = *(const bf16x8*)&Bl[(wc * 64 + nf * 16 + lrow) * 64 + ks * 32 + lk];
#pragma unroll
      for (int mf = 0; mf < 4; ++mf)
#pragma unroll
        for (int nf = 0; nf < 4; ++nf)
          acc[mf][nf] = mfma16(af[mf], bf[nf], acc[mf][nf]);
    }
    __syncthreads();
  }

  const int rb = (l >> 4) * 4;
#pragma unroll
  for (int mf = 0; mf < 4; ++mf) {
#pragma unroll
    for (int nf = 0; nf < 4; ++nf) {
      const int gn = n0 + wc * 64 + nf * 16 + lrow;
      const float bi = bias[gn];
#pragma unroll
      for (int r = 0; r < 4; ++r) {
        const int gm = m0 + wr * 64 + mf * 16 + rb + r;
        const float val = acc[mf][nf][r] + bi;
        if (SPLIT) {
          // [B,H,S,64]: b=gm>>11, s=gm&2047, h=gn>>6, d=gn&63
          const int b = gm >> 11, s = gm & 2047, h = gn >> 6, d = gn & 63;
          ((u16*)outp)[(((size_t)((b * 16 + h) * 2048 + s)) << 6) + d] = f2bf(val);
        } else {
          ((float*)outp)[(size_t)gm * 1024 + gn] = val;
        }
      }
    }
  }
}

__global__ __launch_bounds__(256) void gemm_proj(
    const u16* __restrict__ qb, const u16* __restrict__ wqb,
    const float* __restrict__ b_q, const float* __restrict__ b_k,
    const float* __restrict__ b_v, u16* __restrict__ Qh) {
  const int z = blockIdx.z;
  const float* bias = (z == 0) ? b_q : ((z == 1) ? b_k : b_v);
  gemm_body<true>(qb + ((size_t)z << 22), wqb + ((size_t)z << 20), bias,
                  Qh + ((size_t)z << 22));
}

__global__ __launch_bounds__(256) void gemm_out(
    const u16* __restrict__ X, const u16* __restrict__ W,
    const float* __restrict__ bias, float* __restrict__ out) {
  gemm_body<false>(X, W, bias, out);
}

// ---------------------------------------------------------------------------
// Flash attention: grid (16 q-tiles, 32 bh). Block = 4 waves; wave owns 32 Q
// rows. KV tile = 64. Online softmax; K/V/P staged in LDS with stride 72
// (=144B rows: breaks the 128B-row-stride 16-way bank conflict, keeps 16B
// alignment for ds_read_b128).
// ---------------------------------------------------------------------------
__global__ __launch_bounds__(256) void flash_attn(
    const u16* __restrict__ Qh, const u16* __restrict__ Kh,
    const u16* __restrict__ Vh, u16* __restrict__ AO) {
  __shared__ u16 Kl[64 * 72];
  __shared__ u16 Vt[64 * 72];
  __shared__ u16 Pl[4 * 32 * 72];
  const int tid = threadIdx.x;
  const int wv = tid >> 6, l = tid & 63;
  const int lrow = l & 15, lk = (l >> 4) * 8, rb = (l >> 4) * 4;
  const int qt = blockIdx.x, bh = blockIdx.y;

  const u16* Qp = Qh + ((size_t)bh * 2048 + qt * 128 + wv * 32) * 64;
  const u16* Kp = Kh + (size_t)bh * 2048 * 64;
  const u16* Vp = Vh + (size_t)bh * 2048 * 64;

  bf16x8 qf[2][2];
#pragma unroll
  for (int mi = 0; mi < 2; ++mi)
#pragma unroll
    for (int ks = 0; ks < 2; ++ks)
      qf[mi][ks] = *(const bf16x8*)(Qp + (mi * 16 + lrow) * 64 + ks * 32 + lk);

  f32x4 o[2][4];
  float mx[2][4], ls[2][4];
#pragma unroll
  for (int mi = 0; mi < 2; ++mi) {
#pragma unroll
    for (int df = 0; df < 4; ++df) o[mi][df] = (f32x4){0.f, 0.f, 0.f, 0.f};
#pragma unroll
    for (int r = 0; r < 4; ++r) { mx[mi][r] = -1e30f; ls[mi][r] = 0.f; }
  }

  const int srow = tid >> 3;        // 0..31
  const int scol = (tid & 7) * 8;   // 0..56

  for (int t = 0; t < 32; ++t) {
    const int n0 = t * 64;
    // stage K (row-major, stride 72) and V transposed (stride 72)
#pragma unroll
    for (int p = 0; p < 2; ++p) {
      const int r = p * 32 + srow;
      short8 kv8 = *(const short8*)(Kp + (size_t)(n0 + r) * 64 + scol);
      short8 vv8 = *(const short8*)(Vp + (size_t)(n0 + r) * 64 + scol);
      *(short8*)&Kl[r * 72 + scol] = kv8;
#pragma unroll
      for (int j = 0; j < 8; ++j) Vt[(scol + j) * 72 + r] = (u16)vv8[j];
    }
    __syncthreads();

    // S = Q K^T  (per wave: 32 rows x 64 cols)
    f32x4 s[2][4];
#pragma unroll
    for (int mi = 0; mi < 2; ++mi)
#pragma unroll
      for (int nj = 0; nj < 4; ++nj) s[mi][nj] = (f32x4){0.f, 0.f, 0.f, 0.f};
#pragma unroll
    for (int ks = 0; ks < 2; ++ks) {
      bf16x8 kf[4];
#pragma unroll
      for (int nj = 0; nj < 4; ++nj)
        kf[nj] = *(const bf16x8*)&Kl[(nj * 16 + lrow) * 72 + ks * 32 + lk];
#pragma unroll
      for (int mi = 0; mi < 2; ++mi)
#pragma unroll
        for (int nj = 0; nj < 4; ++nj)
          s[mi][nj] = mfma16(qf[mi][ks], kf[nj], s[mi][nj]);
    }

    // online softmax (row r of lane group = rb+r; 16-lane shfl reduce)
#pragma unroll
    for (int mi = 0; mi < 2; ++mi) {
      float tmax[4] = {-1e30f, -1e30f, -1e30f, -1e30f};
#pragma unroll
      for (int nj = 0; nj < 4; ++nj)
#pragma unroll
        for (int r = 0; r < 4; ++r) {
          s[mi][nj][r] *= 0.125f;
          tmax[r] = fmaxf(tmax[r], s[mi][nj][r]);
        }
#pragma unroll
      for (int msk = 1; msk < 16; msk <<= 1)
#pragma unroll
        for (int r = 0; r < 4; ++r)
          tmax[r] = fmaxf(tmax[r], __shfl_xor(tmax[r], msk));
      float rs[4];
#pragma unroll
      for (int r = 0; r < 4; ++r) {
        const float nm = fmaxf(mx[mi][r], tmax[r]);
        const float sf = __expf(mx[mi][r] - nm);
        mx[mi][r] = nm;
        ls[mi][r] *= sf;
#pragma unroll
        for (int df = 0; df < 4; ++df) o[mi][df][r] *= sf;
        rs[r] = 0.f;
      }
#pragma unroll
      for (int nj = 0; nj < 4; ++nj)
#pragma unroll
        for (int r = 0; r < 4; ++r) {
          const float p = __expf(s[mi][nj][r] - mx[mi][r]);
          rs[r] += p;
          Pl[wv * 2304 + (mi * 16 + rb + r) * 72 + nj * 16 + lrow] = f2bf(p);
        }
#pragma unroll
      for (int msk = 1; msk < 16; msk <<= 1)
#pragma unroll
        for (int r = 0; r < 4; ++r) rs[r] += __shfl_xor(rs[r], msk);
#pragma unroll
      for (int r = 0; r < 4; ++r) ls[mi][r] += rs[r];
    }

    // O += P * V   (P: 32x64 from LDS; V^T: d-major so B-frag is contiguous)
#pragma unroll
    for (int ks = 0; ks < 2; ++ks) {
      bf16x8 pf[2], vf[4];
#pragma unroll
      for (int mi = 0; mi < 2; ++mi)
        pf[mi] = *(const bf16x8*)&Pl[wv * 2304 + (mi * 16 + lrow) * 72 + ks * 32 + lk];
#pragma unroll
      for (int df = 0; df < 4; ++df)
        vf[df] = *(const bf16x8*)&Vt[(df * 16 + lrow) * 72 + ks * 32 + lk];
#pragma unroll
      for (int mi = 0; mi < 2; ++mi)
#pragma unroll
        for (int df = 0; df < 4; ++df)
          o[mi][df] = mfma16(pf[mi], vf[df], o[mi][df]);
    }
    __syncthreads();
  }

  // epilogue: O /= l, write merged [B,S,H*64] bf16
  const int b = bh >> 4, h = bh & 15;
#pragma unroll
  for (int mi = 0; mi < 2; ++mi)
#pragma unroll
    for (int r = 0; r < 4; ++r) {
      const float inv = 1.f / ls[mi][r];
      const int row = qt * 128 + wv * 32 + mi * 16 + rb + r;
#pragma unroll
      for (int df = 0; df < 4; ++df) {
        const int col = h * 64 + df * 16 + lrow;
        AO[((size_t)b * 2048 + row) * 1024 + col] = f2bf(o[mi][df][r] * inv);
      }
    }
}

// ---------------------------------------------------------------------------
extern "C" void kernel_launch(void* const* d_in, const int* in_sizes, int n_in,
                              void* d_out, int out_size, void* d_ws,
                              size_t ws_size, hipStream_t stream) {
  const float* q = (const float*)d_in[0];
  const float* k = (const float*)d_in[1];
  const float* v = (const float*)d_in[2];
  const float* w_q = (const float*)d_in[3];
  const float* b_q = (const float*)d_in[4];
  const float* w_k = (const float*)d_in[5];
  const float* b_k = (const float*)d_in[6];
  const float* w_v = (const float*)d_in[7];
  const float* b_v = (const float*)d_in[8];
  const float* w_o = (const float*)d_in[9];
  const float* b_o = (const float*)d_in[10];

  // ws layout (u16 elements): [0,12M) q/k/v bf16, [12M,16M) weights bf16,
  // [16M,28M) Qh/Kh/Vh split-head bf16, [28M,32M) attention out bf16. 64 MB.
  u16* ws = (u16*)d_ws;
  u16* qb = ws;                       // + z*4M for k,v
  u16* wqb = ws + (12u << 20);        // + z*1M for wk,wv
  u16* wob = ws + (15u << 20);
  u16* Qh = ws + (16u << 20);         // + z*4M for Kh,Vh
  u16* Kh = ws + (20u << 20);
  u16* Vh = ws + (24u << 20);
  u16* AO = ws + (28u << 20);

  cvt_all<<<dim3(8192), dim3(256), 0, stream>>>(q, k, v, w_q, w_k, w_v, w_o, ws);
  gemm_proj<<<dim3(8, 32, 3), dim3(256), 0, stream>>>(qb, wqb, b_q, b_k, b_v, Qh);
  flash_attn<<<dim3(16, 32), dim3(256), 0, stream>>>(Qh, Kh, Vh, AO);
  gemm_out<<<dim3(8, 32), dim3(256), 0, stream>>>(AO, wob, b_o, (float*)d_out);
}

// Round 4
// 168.960 us; speedup vs baseline: 1.4583x; 1.4583x over previous
//
#include <hip/hip_runtime.h>
#include <hip/hip_bf16.h>
#include <stdint.h>

// Problem constants: B=2, S=2048, D_MODEL=1024, H=16, Dk=64. M = B*S = 4096.
typedef unsigned short u16;
typedef __attribute__((ext_vector_type(8))) short short8;
typedef __attribute__((ext_vector_type(8))) __bf16 bf16x8;
typedef __attribute__((ext_vector_type(4))) float f32x4;
typedef __attribute__((ext_vector_type(4))) uint32_t u32x4;

#if defined(__has_builtin)
#if __has_builtin(__builtin_amdgcn_global_load_lds)
#define USE_GLLDS 1
#endif
#endif

__device__ __forceinline__ u16 f2bf(float f) {
  __hip_bfloat16 h = __float2bfloat16(f);
  return __builtin_bit_cast(u16, h);
}

__device__ __forceinline__ f32x4 mfma16(bf16x8 a, bf16x8 b, f32x4 c) {
  return __builtin_amdgcn_mfma_f32_16x16x32_bf16(a, b, c, 0, 0, 0);
}

#ifdef USE_GLLDS
__device__ __forceinline__ void async_cp16(const void* g, void* l) {
  __builtin_amdgcn_global_load_lds(
      (const __attribute__((address_space(1))) void*)g,
      (__attribute__((address_space(3))) void*)l, 16, 0, 0);
}
#endif

// ---------------------------------------------------------------------------
// Kernel 1: fp32 -> bf16 conversion of q,k,v (4M each) and w_q,w_k,w_v,w_o (1M
// each) into one contiguous 16M-element bf16 region at the start of d_ws.
// ---------------------------------------------------------------------------
__global__ __launch_bounds__(256) void cvt_all(
    const float* __restrict__ q, const float* __restrict__ k,
    const float* __restrict__ v, const float* __restrict__ w0,
    const float* __restrict__ w1, const float* __restrict__ w2,
    const float* __restrict__ w3, u16* __restrict__ dst) {
  size_t i = ((size_t)blockIdx.x * 256 + threadIdx.x) * 8;
  const size_t M1 = 1u << 20;
  const float* s;
  size_t base;
  if (i < 4 * M1) { s = q; base = 0; }
  else if (i < 8 * M1) { s = k; base = 4 * M1; }
  else if (i < 12 * M1) { s = v; base = 8 * M1; }
  else if (i < 13 * M1) { s = w0; base = 12 * M1; }
  else if (i < 14 * M1) { s = w1; base = 13 * M1; }
  else if (i < 15 * M1) { s = w2; base = 14 * M1; }
  else { s = w3; base = 15 * M1; }
  const float4 a = *(const float4*)(s + (i - base));
  const float4 b = *(const float4*)(s + (i - base) + 4);
  short8 r;
  r[0] = (short)f2bf(a.x); r[1] = (short)f2bf(a.y);
  r[2] = (short)f2bf(a.z); r[3] = (short)f2bf(a.w);
  r[4] = (short)f2bf(b.x); r[5] = (short)f2bf(b.y);
  r[6] = (short)f2bf(b.z); r[7] = (short)f2bf(b.w);
  *(short8*)(dst + i) = r;
}

// ---------------------------------------------------------------------------
// GEMM: C[M=4096, N=1024] = X[4096,1024] * W[1024,1024]^T + bias.
// 128x128 tile, BK=64, 4 waves. Epilogue modes:
//   0: Q  -> bf16 split-head [B,H,S,64], scaled by 1/8 (folded softmax scale)
//   1: K  -> bf16 split-head [B,H,S,64]
//   2: V  -> bf16 TRANSPOSED split-head [B,H,64,S]  (V^T for the PV mfma)
//   3: fp32 row-major [4096,1024] (output projection)
// ---------------------------------------------------------------------------
__device__ __forceinline__ void gemm_body(const u16* __restrict__ X,
                                          const u16* __restrict__ W,
                                          const float* __restrict__ bias,
                                          void* __restrict__ outp, int mode) {
  __shared__ u16 Al[128 * 64];
  __shared__ u16 Bl[128 * 64];
  const int tid = threadIdx.x;
  const int wv = tid >> 6, l = tid & 63;
  const int wr = wv >> 1, wc = wv & 1;
  const int m0 = blockIdx.y * 128, n0 = blockIdx.x * 128;
  const int lrow = l & 15, lk = (l >> 4) * 8;

  f32x4 acc[4][4];
#pragma unroll
  for (int i = 0; i < 4; ++i)
#pragma unroll
    for (int j = 0; j < 4; ++j) acc[i][j] = (f32x4){0.f, 0.f, 0.f, 0.f};

  const u16* Asrc = X + (size_t)(m0 + (tid >> 3)) * 1024 + (tid & 7) * 8;
  const u16* Bsrc = W + (size_t)(n0 + (tid >> 3)) * 1024 + (tid & 7) * 8;

  for (int kt = 0; kt < 1024; kt += 64) {
#ifdef USE_GLLDS
#pragma unroll
    for (int p = 0; p < 4; ++p) {
      async_cp16(Asrc + (size_t)p * 32 * 1024 + kt, &Al[p * 2048 + wv * 512]);
      async_cp16(Bsrc + (size_t)p * 32 * 1024 + kt, &Bl[p * 2048 + wv * 512]);
    }
#else
    short8 ar[4], br[4];
#pragma unroll
    for (int p = 0; p < 4; ++p) {
      ar[p] = *(const short8*)(Asrc + (size_t)p * 32 * 1024 + kt);
      br[p] = *(const short8*)(Bsrc + (size_t)p * 32 * 1024 + kt);
    }
#pragma unroll
    for (int p = 0; p < 4; ++p) {
      *(short8*)&Al[p * 2048 + tid * 8] = ar[p];
      *(short8*)&Bl[p * 2048 + tid * 8] = br[p];
    }
#endif
    __syncthreads();
#pragma unroll
    for (int ks = 0; ks < 2; ++ks) {
      bf16x8 af[4], bf[4];
#pragma unroll
      for (int mf = 0; mf < 4; ++mf)
        af[mf] = *(const bf16x8*)&Al[(wr * 64 + mf * 16 + lrow) * 64 + ks * 32 + lk];
#pragma unroll
      for (int nf = 0; nf < 4; ++nf)
        bf[nf] = *(const bf16x8*)&Bl[(wc * 64 + nf * 16 + lrow) * 64 + ks * 32 + lk];
#pragma unroll
      for (int mf = 0; mf < 4; ++mf)
#pragma unroll
        for (int nf = 0; nf < 4; ++nf)
          acc[mf][nf] = mfma16(af[mf], bf[nf], acc[mf][nf]);
    }
    __syncthreads();
  }

  const int rb = (l >> 4) * 4;
#pragma unroll
  for (int mf = 0; mf < 4; ++mf) {
#pragma unroll
    for (int nf = 0; nf < 4; ++nf) {
      const int gn = n0 + wc * 64 + nf * 16 + lrow;
      const float bi = bias[gn];
#pragma unroll
      for (int r = 0; r < 4; ++r) {
        const int gm = m0 + wr * 64 + mf * 16 + rb + r;
        float val = acc[mf][nf][r] + bi;
        const int b = gm >> 11, s = gm & 2047, h = gn >> 6, d = gn & 63;
        if (mode == 3) {
          ((float*)outp)[(size_t)gm * 1024 + gn] = val;
        } else if (mode == 2) {
          // V^T: [B,H,64,S]
          ((u16*)outp)[(((size_t)((b * 16 + h) * 64 + d)) << 11) + s] = f2bf(val);
        } else {
          if (mode == 0) val *= 0.125f;  // fold 1/sqrt(Dk) into Q
          ((u16*)outp)[(((size_t)((b * 16 + h) * 2048 + s)) << 6) + d] = f2bf(val);
        }
      }
    }
  }
}

__global__ __launch_bounds__(256) void gemm_proj(
    const u16* __restrict__ qb, const u16* __restrict__ wqb,
    const float* __restrict__ b_q, const float* __restrict__ b_k,
    const float* __restrict__ b_v, u16* __restrict__ Qh) {
  const int z = blockIdx.z;
  const float* bias = (z == 0) ? b_q : ((z == 1) ? b_k : b_v);
  gemm_body(qb + ((size_t)z << 22), wqb + ((size_t)z << 20), bias,
            Qh + ((size_t)z << 22), z);
}

__global__ __launch_bounds__(256) void gemm_out(
    const u16* __restrict__ X, const u16* __restrict__ W,
    const float* __restrict__ bias, float* __restrict__ out) {
  gemm_body(X, W, bias, out, 3);
}

// ---------------------------------------------------------------------------
// Flash attention v2: swapped-operand structure.
//   S = mfma(A=K, B=Q)    -> D[k][q], lane holds q = l&15 (row softmax cheap)
//   O^T = mfma(A=V^T, B=P) -> D[d][q], same lane mapping for m/ls/o
// Block = 8 waves x 16 q-rows = 128 rows. Grid (16, 32). KV tile = 64.
// K and V^T tiles staged via global_load_lds with XOR-swizzled SOURCE
// (linear LDS dest, swizzled ds_read: quad col ^= (row&7)) -> conflict-free
// b128 reads. P goes through a per-wave LDS slab (no barrier; same-wave).
// One __syncthreads per tile (2-phase double buffer).
// ---------------------------------------------------------------------------
__global__ __launch_bounds__(512, 4) void flash_attn2(
    const u16* __restrict__ Qh, const u16* __restrict__ Kh,
    const u16* __restrict__ VT, u16* __restrict__ AO) {
  __shared__ __align__(16) u16 Kbuf[2][4096];   // 64 rows x 128B, swizzled
  __shared__ __align__(16) u16 Vbuf[2][4096];   // 64 d-rows x 128B, swizzled
  __shared__ __align__(16) uint32_t Pl[8 * 576]; // per-wave 16 x 36 dwords

  const int tid = threadIdx.x;
  const int wv = tid >> 6, l = tid & 63;
  const int q = l & 15, g = l >> 4;
  const int qt = blockIdx.x, bh = blockIdx.y;

  const u16* Qp = Qh + ((size_t)bh * 2048 + qt * 128 + wv * 16) * 64;
  const u16* Kp = Kh + (size_t)bh * 2048 * 64;
  const u16* Vp = VT + (size_t)bh * 64 * 2048;

  // Q fragments (B-operand): lane holds Q[q=l&15][d = ks*32 + g*8 .. +7]
  bf16x8 qf[2];
  qf[0] = *(const bf16x8*)(Qp + q * 64 + g * 8);
  qf[1] = *(const bf16x8*)(Qp + q * 64 + 32 + g * 8);

  f32x4 o[4];
#pragma unroll
  for (int df = 0; df < 4; ++df) o[df] = (f32x4){0.f, 0.f, 0.f, 0.f};
  float m = -1e30f, ls = 0.f;

  // staging constants: wave wv stages rows wv*8..wv*8+7 of each tile (1KB)
  const int srow = l >> 3;                       // 0..7 within wave's 8 rows
  const int scolq = (l & 7) ^ srow;              // inverse-swizzled 16B chunk
  const int pbase = wv * 576 + q * 36;
  const char* kb0 = (const char*)&Kbuf[0][0];
  const char* kb1 = (const char*)&Kbuf[1][0];
  const char* vb0 = (const char*)&Vbuf[0][0];
  const char* vb1 = (const char*)&Vbuf[1][0];
  const int rsw = (q & 7) << 4;                  // read swizzle (byte)

#ifdef USE_GLLDS
#define STAGE(buf, t)                                                         \
  do {                                                                        \
    const int n0_ = (t) * 64;                                                 \
    const u16* kg_ = Kp + (size_t)(n0_ + wv * 8 + srow) * 64 + scolq * 8;     \
    const u16* vg_ = Vp + (size_t)(wv * 8 + srow) * 2048 + n0_ + scolq * 8;   \
    async_cp16(kg_, &Kbuf[buf][wv * 512]);                                    \
    async_cp16(vg_, &Vbuf[buf][wv * 512]);                                    \
  } while (0)
#else
#define STAGE(buf, t)                                                         \
  do {                                                                        \
    const int n0_ = (t) * 64;                                                 \
    const u16* kg_ = Kp + (size_t)(n0_ + wv * 8 + srow) * 64 + scolq * 8;     \
    const u16* vg_ = Vp + (size_t)(wv * 8 + srow) * 2048 + n0_ + scolq * 8;   \
    short8 kt_ = *(const short8*)kg_;                                         \
    short8 vt_ = *(const short8*)vg_;                                         \
    *(short8*)&Kbuf[buf][wv * 512 + l * 8] = kt_;                             \
    *(short8*)&Vbuf[buf][wv * 512 + l * 8] = vt_;                             \
  } while (0)
#endif

  STAGE(0, 0);
  __syncthreads();

  for (int t = 0; t < 32; ++t) {
    const int cur = t & 1;
    if (t < 31) STAGE(cur ^ 1, t + 1);

    const char* kb = cur ? kb1 : kb0;
    const char* vb = cur ? vb1 : vb0;

    // ---- S = K . Q'  -> s[nj] holds k = nj*16 + 4g + r, for q = l&15
    f32x4 s[4];
#pragma unroll
    for (int nj = 0; nj < 4; ++nj) s[nj] = (f32x4){0.f, 0.f, 0.f, 0.f};
#pragma unroll
    for (int ks = 0; ks < 2; ++ks) {
#pragma unroll
      for (int nj = 0; nj < 4; ++nj) {
        bf16x8 kf = *(const bf16x8*)(kb + (nj * 16 + q) * 128 +
                                     (((ks * 4 + g) << 4) ^ rsw));
        s[nj] = mfma16(kf, qf[ks], s[nj]);
      }
    }

    // ---- online softmax: row q spread over lanes {l, l^16, l^32, l^48}
    float mt = s[0][0];
#pragma unroll
    for (int nj = 0; nj < 4; ++nj)
#pragma unroll
      for (int r = 0; r < 4; ++r) mt = fmaxf(mt, s[nj][r]);
    mt = fmaxf(mt, __shfl_xor(mt, 16));
    mt = fmaxf(mt, __shfl_xor(mt, 32));
    const float nm = fmaxf(m, mt);
    const float rf = __expf(m - nm);
    m = nm;
    float ps = 0.f;
#pragma unroll
    for (int nj = 0; nj < 4; ++nj)
#pragma unroll
      for (int r = 0; r < 4; ++r) {
        s[nj][r] = __expf(s[nj][r] - nm);
        ps += s[nj][r];
      }
    ps += __shfl_xor(ps, 16);
    ps += __shfl_xor(ps, 32);
    ls = ls * rf + ps;
#pragma unroll
    for (int df = 0; df < 4; ++df) o[df] *= rf;

    // ---- P -> LDS (packed bf16 pairs), per-wave slab, same-wave reuse
#pragma unroll
    for (int nj = 0; nj < 4; ++nj)
#pragma unroll
      for (int pp = 0; pp < 2; ++pp) {
        uint32_t w = (uint32_t)f2bf(s[nj][2 * pp]) |
                     ((uint32_t)f2bf(s[nj][2 * pp + 1]) << 16);
        Pl[pbase + nj * 8 + g * 2 + pp] = w;
      }

    // ---- O^T += V^T . P : lane q = l&15, d = df*16 + 4g + r
#pragma unroll
    for (int ks = 0; ks < 2; ++ks) {
      u32x4 pw = *(const u32x4*)&Pl[pbase + ks * 16 + 4 * g];
      bf16x8 pf = __builtin_bit_cast(bf16x8, pw);
#pragma unroll
      for (int df = 0; df < 4; ++df) {
        bf16x8 vf = *(const bf16x8*)(vb + (df * 16 + q) * 128 +
                                     (((ks * 4 + g) << 4) ^ rsw));
        o[df] = mfma16(vf, pf, o[df]);
      }
    }
    __syncthreads();
  }

  // ---- epilogue: O /= ls, write merged [B,S,H*64] bf16 (paired u32 stores)
  const float inv = 1.f / ls;
  const int b = bh >> 4, h = bh & 15;
  u16* Ap = AO + ((size_t)(b * 2048 + qt * 128 + wv * 16 + q)) * 1024 + h * 64;
#pragma unroll
  for (int df = 0; df < 4; ++df)
#pragma unroll
    for (int pp = 0; pp < 2; ++pp) {
      uint32_t w = (uint32_t)f2bf(o[df][2 * pp] * inv) |
                   ((uint32_t)f2bf(o[df][2 * pp + 1] * inv) << 16);
      *(uint32_t*)(Ap + df * 16 + 4 * g + 2 * pp) = w;
    }
}

// ---------------------------------------------------------------------------
extern "C" void kernel_launch(void* const* d_in, const int* in_sizes, int n_in,
                              void* d_out, int out_size, void* d_ws,
                              size_t ws_size, hipStream_t stream) {
  const float* q = (const float*)d_in[0];
  const float* k = (const float*)d_in[1];
  const float* v = (const float*)d_in[2];
  const float* w_q = (const float*)d_in[3];
  const float* b_q = (const float*)d_in[4];
  const float* w_k = (const float*)d_in[5];
  const float* b_k = (const float*)d_in[6];
  const float* w_v = (const float*)d_in[7];
  const float* b_v = (const float*)d_in[8];
  const float* w_o = (const float*)d_in[9];
  const float* b_o = (const float*)d_in[10];

  // ws layout (u16 elements): [0,12M) q/k/v bf16, [12M,16M) weights bf16,
  // [16M,20M) Qh (scaled), [20M,24M) Kh, [24M,28M) V^T, [28M,32M) attn out.
  u16* ws = (u16*)d_ws;
  u16* qb = ws;                       // + z*4M for k,v
  u16* wqb = ws + (12u << 20);        // + z*1M for wk,wv
  u16* wob = ws + (15u << 20);
  u16* Qh = ws + (16u << 20);         // z=0
  u16* Kh = ws + (20u << 20);         // z=1
  u16* VT = ws + (24u << 20);         // z=2 (transposed)
  u16* AO = ws + (28u << 20);

  cvt_all<<<dim3(8192), dim3(256), 0, stream>>>(q, k, v, w_q, w_k, w_v, w_o, ws);
  gemm_proj<<<dim3(8, 32, 3), dim3(256), 0, stream>>>(qb, wqb, b_q, b_k, b_v, Qh);
  flash_attn2<<<dim3(16, 32), dim3(512), 0, stream>>>(Qh, Kh, VT, AO);
  gemm_out<<<dim3(8, 32), dim3(256), 0, stream>>>(AO, wob, b_o, (float*)d_out);
}